// Round 3
// baseline (469.877 us; speedup 1.0000x reference)
//
#include <hip/hip_runtime.h>

#define NN 100000
#define NE 1600000
#define NG 512

#define BSH 9                         // bucket = dst >> 9 (512 nodes/bucket)
#define NB 196                        // ceil(NN / 512)
#define EPB 8192                      // edges per block in phase A
#define NAB ((NE + EPB - 1) / EPB)    // 196 phase-A blocks
#define CAP 9216                      // LDS staging capacity in kB_build

// ---------- embedding lookup + pre-linear + relu: x1[N,32] ----------
__global__ __launch_bounds__(256) void k_embed(
    const int* __restrict__ nf, const float* __restrict__ semb,
    const float* __restrict__ cemb, const float* __restrict__ pw,
    const float* __restrict__ pb, float* __restrict__ x1)
{
  int gid = blockIdx.x * 256 + threadIdx.x;
  bool valid = gid < NN;
  int i = valid ? gid : NN - 1;
  int sf = nf[2 * i], cf = nf[2 * i + 1];
  float x0[16];
#pragma unroll
  for (int k = 0; k < 8; ++k) x0[k] = semb[sf * 8 + k];
#pragma unroll
  for (int k = 0; k < 8; ++k) x0[8 + k] = cemb[cf * 8 + k];
  float acc[32];
#pragma unroll
  for (int j = 0; j < 32; ++j) acc[j] = pb[j];
#pragma unroll
  for (int k = 0; k < 16; ++k) {
    float xv = x0[k];
#pragma unroll
    for (int j = 0; j < 32; ++j) acc[j] += xv * pw[k * 32 + j];
  }
  if (valid) {
    float4* o = (float4*)(x1 + (size_t)i * 32);
#pragma unroll
    for (int j4 = 0; j4 < 8; ++j4) {
      float4 v;
      v.x = fmaxf(acc[4 * j4 + 0], 0.f);
      v.y = fmaxf(acc[4 * j4 + 1], 0.f);
      v.z = fmaxf(acc[4 * j4 + 2], 0.f);
      v.w = fmaxf(acc[4 * j4 + 3], 0.f);
      o[j4] = v;
    }
  }
}

// ---------- CSR build via bucketed counting sort ----------

// Phase A1: per-bucket edge counts (LDS histogram, 1 global atomic/bucket/block)
__global__ __launch_bounds__(256) void kA_count(
    const int* __restrict__ ei, int* __restrict__ bkt_cnt)
{
  __shared__ int lh[NB];
  for (int b = threadIdx.x; b < NB; b += 256) lh[b] = 0;
  __syncthreads();
  int base = blockIdx.x * EPB;
#pragma unroll
  for (int i = 0; i < EPB / 256; ++i) {
    int e = base + i * 256 + threadIdx.x;
    if (e < NE) atomicAdd(&lh[ei[NE + e] >> BSH], 1);
  }
  __syncthreads();
  for (int b = threadIdx.x; b < NB; b += 256)
    if (lh[b]) atomicAdd(&bkt_cnt[b], lh[b]);
}

// Phase A2: exclusive scan over the 196 bucket counts -> base + cursor
__global__ __launch_bounds__(256) void kA_scan(
    const int* __restrict__ bkt_cnt, int* __restrict__ bkt_base,
    int* __restrict__ bkt_cur)
{
  __shared__ int sm[2][256];
  int t = threadIdx.x;
  int v = (t < NB) ? bkt_cnt[t] : 0;
  sm[0][t] = v;
  __syncthreads();
  int cur = 0;
#pragma unroll
  for (int off = 1; off < 256; off <<= 1) {
    int add = (t >= off) ? sm[cur][t - off] : 0;
    sm[cur ^ 1][t] = sm[cur][t] + add;
    __syncthreads();
    cur ^= 1;
  }
  if (t < NB) {
    int ex = sm[cur][t] - v;
    bkt_base[t] = ex;
    bkt_cur[t] = ex;
  }
  if (t == 0) bkt_base[NB] = NE;
}

// Phase A3: bin edges by bucket; one contiguous run reservation per bucket per
// block -> dense burst writes from one CU.
// pack: src(0-16) | type(17-18) | dst&511 (19-27)
__global__ __launch_bounds__(256) void kA_scatter(
    const int* __restrict__ ei, const int* __restrict__ et,
    int* __restrict__ bkt_cur, int* __restrict__ binned)
{
  __shared__ int packA[EPB];
  __shared__ unsigned char bktA[EPB];
  __shared__ int lh[NB], grun[NB], lcur[NB];
  for (int b = threadIdx.x; b < NB; b += 256) { lh[b] = 0; lcur[b] = 0; }
  __syncthreads();
  int base = blockIdx.x * EPB;
#pragma unroll
  for (int i = 0; i < EPB / 256; ++i) {
    int p = i * 256 + threadIdx.x;
    int e = base + p;
    if (e < NE) {
      int src = ei[e], dst = ei[NE + e], ty = et[e];
      int b = dst >> BSH;
      packA[p] = src | (ty << 17) | ((dst & 511) << 19);
      bktA[p] = (unsigned char)b;
      atomicAdd(&lh[b], 1);
    } else {
      bktA[p] = 255;
    }
  }
  __syncthreads();
  for (int b = threadIdx.x; b < NB; b += 256)
    grun[b] = lh[b] ? atomicAdd(&bkt_cur[b], lh[b]) : 0;
  __syncthreads();
#pragma unroll
  for (int i = 0; i < EPB / 256; ++i) {
    int p = i * 256 + threadIdx.x;
    int b = bktA[p];
    if (b != 255) {
      int off = atomicAdd(&lcur[b], 1);
      binned[grun[b] + off] = packA[p];
    }
  }
}

// Phase B: one workgroup per bucket; exclusive contiguous slice of ep.
__global__ __launch_bounds__(512) void kB_build(
    const int* __restrict__ bkt_base, const int* __restrict__ binned,
    int* __restrict__ rs, int* __restrict__ ep)
{
  __shared__ int stage[CAP];
  __shared__ int ldeg[512], lrs[512], lcur[512];
  __shared__ int sm[2][512];
  int b = blockIdx.x;
  int t = threadIdx.x;
  int p0 = bkt_base[b], p1 = bkt_base[b + 1];
  int cnt = p1 - p0;
  int nodes0 = b << BSH;
  int nnodes = NN - nodes0 < 512 ? NN - nodes0 : 512;
  ldeg[t] = 0;
  lcur[t] = 0;
  __syncthreads();
  for (int p = t; p < cnt; p += 512) {
    int pk = binned[p0 + p];
    if (p < CAP) stage[p] = pk;
    atomicAdd(&ldeg[(pk >> 19) & 511], 1);
  }
  __syncthreads();
  sm[0][t] = ldeg[t];
  __syncthreads();
  int cur = 0;
#pragma unroll
  for (int off = 1; off < 512; off <<= 1) {
    int add = (t >= off) ? sm[cur][t - off] : 0;
    sm[cur ^ 1][t] = sm[cur][t] + add;
    __syncthreads();
    cur ^= 1;
  }
  lrs[t] = p0 + sm[cur][t] - ldeg[t];
  if (t < nnodes) rs[nodes0 + t] = lrs[t];
  if (b == NB - 1 && t == 0) rs[NN] = NE;
  __syncthreads();
  for (int p = t; p < cnt; p += 512) {
    int pk = (p < CAP) ? stage[p] : binned[p0 + p];
    int dl = (pk >> 19) & 511;
    int off = atomicAdd(&lcur[dl], 1);
    ep[lrs[dl] + off] = pk & 0x7FFFF;  // keep src|type bits only
  }
}

// ---------- per-relation mean aggregation: h[d][r][k] = mean_{(s->d,r)} x[s][k] ----------
template <int IN>
__global__ __launch_bounds__(256) void k_agg(
    const float* __restrict__ x, const int* __restrict__ rs,
    const int* __restrict__ ep, float* __restrict__ h)
{
  constexpr int DPW = 64 / IN;  // dst per wave
  int tid = threadIdx.x;
  int wid = (blockIdx.x * 256 + tid) >> 6;
  int lane = tid & 63;
  int k = lane & (IN - 1);
  int half = lane >> (IN == 64 ? 6 : 5);  // 0, or 0/1 when IN=32
  int d = wid * DPW + half;
  if (d >= NN) return;
  int p0 = rs[d], p1 = rs[d + 1];
  float a0 = 0.f, a1 = 0.f, a2 = 0.f;
  int c0 = 0, c1 = 0, c2 = 0;
  int p = p0;
  for (; p + 4 <= p1; p += 4) {
    int e0 = ep[p + 0];
    int e1 = ep[p + 1];
    int e2 = ep[p + 2];
    int e3 = ep[p + 3];
    float v0 = x[(size_t)(e0 & 0x1FFFF) * IN + k];
    float v1 = x[(size_t)(e1 & 0x1FFFF) * IN + k];
    float v2 = x[(size_t)(e2 & 0x1FFFF) * IN + k];
    float v3 = x[(size_t)(e3 & 0x1FFFF) * IN + k];
    int t0 = e0 >> 17, t1 = e1 >> 17, t2 = e2 >> 17, t3 = e3 >> 17;
    a0 += ((t0 == 0) ? v0 : 0.f) + ((t1 == 0) ? v1 : 0.f) +
          ((t2 == 0) ? v2 : 0.f) + ((t3 == 0) ? v3 : 0.f);
    a1 += ((t0 == 1) ? v0 : 0.f) + ((t1 == 1) ? v1 : 0.f) +
          ((t2 == 1) ? v2 : 0.f) + ((t3 == 1) ? v3 : 0.f);
    a2 += ((t0 == 2) ? v0 : 0.f) + ((t1 == 2) ? v1 : 0.f) +
          ((t2 == 2) ? v2 : 0.f) + ((t3 == 2) ? v3 : 0.f);
    c0 += (t0 == 0) + (t1 == 0) + (t2 == 0) + (t3 == 0);
    c1 += (t0 == 1) + (t1 == 1) + (t2 == 1) + (t3 == 1);
    c2 += (t0 == 2) + (t1 == 2) + (t2 == 2) + (t3 == 2);
  }
  for (; p < p1; ++p) {
    int e = ep[p];
    float v = x[(size_t)(e & 0x1FFFF) * IN + k];
    int t = e >> 17;
    a0 += (t == 0) ? v : 0.f;
    a1 += (t == 1) ? v : 0.f;
    a2 += (t == 2) ? v : 0.f;
    c0 += (t == 0);
    c1 += (t == 1);
    c2 += (t == 2);
  }
  float* hd = h + (size_t)d * 3 * IN;
  hd[0 * IN + k] = a0 / (float)(c0 > 0 ? c0 : 1);
  hd[1 * IN + k] = a1 / (float)(c1 > 0 ? c1 : 1);
  hd[2 * IN + k] = a2 / (float)(c2 > 0 ? c2 : 1);
}

// ---------- dense: y[d] = relu(x[d]@root + bias + sum_r h[d][r]@rel_r) ----------
// j-split x8: each thread computes an 8-wide output chunk. Grid = 8x node
// blocks = 3136 -> >8 blocks/CU so the 8-block VGPR cap (32 waves/CU) stays
// saturated. The 4 input streams (x, h0, h1, h2) are loaded in ONE merged
// k-loop -> 4 independent float4 loads in flight per iteration, 128 FMAs per
// 4 loads; unroll-4 lets the compiler hoist next-iteration loads under FMAs.
// blockIdx swizzle: bid = super<<6 | jc<<3 | slot keeps all 8 j-chunk
// siblings of a node-block on the same XCD (round-robin dispatch) -> row
// re-reads are L2 hits and the 32B stores merge into full lines in that L2.
template <int IN>
__global__ __launch_bounds__(256) void k_mat(
    const float* __restrict__ x, const float* __restrict__ h,
    const float* __restrict__ root, const float* __restrict__ rel,
    const float* __restrict__ bias, float* __restrict__ y)
{
  int bid = blockIdx.x;
  int jc = (bid >> 3) & 7;
  int nb = ((bid >> 6) << 3) | (bid & 7);
  int gid = nb * 256 + threadIdx.x;
  bool valid = gid < NN;
  int i = valid ? gid : NN - 1;
  int j0 = jc * 8;

  float acc[8];
#pragma unroll
  for (int j = 0; j < 8; ++j) acc[j] = bias[j0 + j];

  const float4* X0 = (const float4*)(x + (size_t)i * IN);
  const float4* X1 = (const float4*)(h + (size_t)i * 3 * IN);
  const float4* X2 = X1 + IN / 4;
  const float4* X3 = X2 + IN / 4;
  const float* W0 = root + j0;
  const float* W1 = rel + j0;
  const float* W2 = rel + (size_t)IN * 64 + j0;
  const float* W3 = rel + (size_t)2 * IN * 64 + j0;

#pragma unroll 4
  for (int k4 = 0; k4 < IN / 4; ++k4) {
    float4 a = X0[k4];
    float4 b = X1[k4];
    float4 c = X2[k4];
    float4 d = X3[k4];
#pragma unroll
    for (int kk = 0; kk < 4; ++kk) {
      int k = k4 * 4 + kk;
      float sa = ((const float*)&a)[kk];
      float sb = ((const float*)&b)[kk];
      float sc = ((const float*)&c)[kk];
      float sd = ((const float*)&d)[kk];
      const float* w0 = W0 + (size_t)k * 64;
      const float* w1 = W1 + (size_t)k * 64;
      const float* w2 = W2 + (size_t)k * 64;
      const float* w3 = W3 + (size_t)k * 64;
#pragma unroll
      for (int j = 0; j < 8; ++j) acc[j] = fmaf(sa, w0[j], acc[j]);
#pragma unroll
      for (int j = 0; j < 8; ++j) acc[j] = fmaf(sb, w1[j], acc[j]);
#pragma unroll
      for (int j = 0; j < 8; ++j) acc[j] = fmaf(sc, w2[j], acc[j]);
#pragma unroll
      for (int j = 0; j < 8; ++j) acc[j] = fmaf(sd, w3[j], acc[j]);
    }
  }
  if (valid) {
    float4* o = (float4*)(y + (size_t)i * 64 + j0);
#pragma unroll
    for (int j4 = 0; j4 < 2; ++j4) {
      float4 v;
      v.x = fmaxf(acc[4 * j4 + 0], 0.f);
      v.y = fmaxf(acc[4 * j4 + 1], 0.f);
      v.z = fmaxf(acc[4 * j4 + 2], 0.f);
      v.w = fmaxf(acc[4 * j4 + 3], 0.f);
      o[j4] = v;
    }
  }
}

// ---------- mean pool over sorted batch ids (run-length reduce, then atomic) ----------
__global__ __launch_bounds__(256) void k_pool(
    const float* __restrict__ x3, const int* __restrict__ batch,
    float* __restrict__ pooled, float* __restrict__ gcnt)
{
  int gwave = (blockIdx.x * 256 + threadIdx.x) >> 6;
  int lane = threadIdx.x & 63;
  int n0 = gwave * 64;
  if (n0 >= NN) return;
  int n1 = n0 + 64 < NN ? n0 + 64 : NN;
  int gcur = batch[n0];
  float acc = 0.f;
  int run = 0;
  for (int n = n0; n < n1; ++n) {
    int g = batch[n];
    if (g != gcur) {
      atomicAdd(&pooled[gcur * 64 + lane], acc);
      if (lane == 0) atomicAdd(&gcnt[gcur], (float)run);
      acc = 0.f; run = 0; gcur = g;
    }
    acc += x3[(size_t)n * 64 + lane];
    ++run;
  }
  atomicAdd(&pooled[gcur * 64 + lane], acc);
  if (lane == 0) atomicAdd(&gcnt[gcur], (float)run);
}

// ---------- classifier ----------
__global__ __launch_bounds__(256) void k_cls(
    const float* __restrict__ pooled, const float* __restrict__ gcnt,
    const float* __restrict__ cw, const float* __restrict__ cb, float* __restrict__ out)
{
  int t = blockIdx.x * 256 + threadIdx.x;
  if (t >= NG * 10) return;
  int g = t / 10, c = t % 10;
  float cf = fmaxf(gcnt[g], 1.f);
  float acc = cb[c];
#pragma unroll 8
  for (int k = 0; k < 64; ++k)
    acc += (pooled[g * 64 + k] / cf) * cw[k * 10 + c];
  out[t] = acc;
}

extern "C" void kernel_launch(void* const* d_in, const int* in_sizes, int n_in,
                              void* d_out, int out_size, void* d_ws, size_t ws_size,
                              hipStream_t stream)
{
  const int* nf = (const int*)d_in[0];
  const int* ei = (const int*)d_in[1];
  const int* et = (const int*)d_in[2];
  const int* batch = (const int*)d_in[3];
  const float* semb = (const float*)d_in[4];
  const float* cemb = (const float*)d_in[5];
  const float* pw = (const float*)d_in[6];
  const float* pb = (const float*)d_in[7];
  const float* root1 = (const float*)d_in[8];
  const float* rel1 = (const float*)d_in[9];
  const float* bias1 = (const float*)d_in[10];
  const float* root2 = (const float*)d_in[11];
  const float* rel2 = (const float*)d_in[12];
  const float* bias2 = (const float*)d_in[13];
  const float* cw = (const float*)d_in[14];
  const float* cb = (const float*)d_in[15];
  float* out = (float*)d_out;

  char* ws = (char*)d_ws;
  size_t off = 0;
  auto alloc = [&](size_t bytes) {
    char* p = ws + off;
    off += (bytes + 255) & ~(size_t)255;
    return p;
  };
  int* bkt_cnt = (int*)alloc((size_t)NB * 4);
  int* bkt_base = (int*)alloc((size_t)(NB + 1) * 4);
  int* bkt_cur = (int*)alloc((size_t)NB * 4);
  int* rs = (int*)alloc((size_t)(NN + 1) * 4);     // row_start
  int* ep = (int*)alloc((size_t)NE * 4);           // packed (src | type<<17), CSR order
  float* xA = (float*)alloc((size_t)NN * 64 * 4);  // x2
  float* xB = (float*)alloc((size_t)NN * 64 * 4);  // x1 ([N,32]) then x3
  float* h = (float*)alloc((size_t)3 * NN * 64 * 4);  // h[d][r][IN]
  float* pooled = (float*)alloc((size_t)NG * 64 * 4);
  float* gcnt = (float*)alloc((size_t)NG * 4);
  int* binned = (int*)h;  // phase-A output; consumed by kB_build before k_agg writes h
  (void)ws_size; (void)in_sizes; (void)n_in; (void)out_size;

  hipMemsetAsync(bkt_cnt, 0, (size_t)NB * 4, stream);
  k_embed<<<(NN + 255) / 256, 256, 0, stream>>>(nf, semb, cemb, pw, pb, xB);

  // CSR build: bucketed counting sort
  kA_count<<<NAB, 256, 0, stream>>>(ei, bkt_cnt);
  kA_scan<<<1, 256, 0, stream>>>(bkt_cnt, bkt_base, bkt_cur);
  kA_scatter<<<NAB, 256, 0, stream>>>(ei, et, bkt_cur, binned);
  kB_build<<<NB, 512, 0, stream>>>(bkt_base, binned, rs, ep);

  // node-blocks padded to a multiple of 8 so the j-chunk/XCD swizzle is clean
  int nblk = (NN + 255) / 256;          // 391
  int nblk8 = (nblk + 7) & ~7;          // 392
  int matgrid = nblk8 * 8;              // 3136

  // layer 1: x1[N,32] (xB) -> h -> x2[N,64] (xA)
  k_agg<32><<<(NN / 2 + 3) / 4 + 1, 256, 0, stream>>>(xB, rs, ep, h);
  k_mat<32><<<matgrid, 256, 0, stream>>>(xB, h, root1, rel1, bias1, xA);
  // layer 2: x2 (xA) -> h -> x3 (xB)
  k_agg<64><<<(NN + 3) / 4, 256, 0, stream>>>(xA, rs, ep, h);
  k_mat<64><<<matgrid, 256, 0, stream>>>(xA, h, root2, rel2, bias2, xB);

  hipMemsetAsync(pooled, 0, (size_t)NG * 64 * 4, stream);
  hipMemsetAsync(gcnt, 0, (size_t)NG * 4, stream);
  int nwaves = (NN + 63) / 64;
  k_pool<<<(nwaves + 3) / 4, 256, 0, stream>>>(xB, batch, pooled, gcnt);
  k_cls<<<(NG * 10 + 255) / 256, 256, 0, stream>>>(pooled, gcnt, cw, cb, out);
}

// Round 4
// 345.408 us; speedup vs baseline: 1.3604x; 1.3604x over previous
//
#include <hip/hip_runtime.h>

#define NN 100000
#define NE 1600000
#define NG 512

#define BSH 9                         // bucket = dst >> 9 (512 nodes/bucket)
#define NB 196                        // ceil(NN / 512)
#define EPB 8192                      // edges per block in phase A
#define NAB ((NE + EPB - 1) / EPB)    // 196 phase-A blocks
#define CAP 9216                      // LDS staging capacity in kB_build

// ---------- embedding lookup + pre-linear + relu: x1[N,32] ----------
__global__ __launch_bounds__(256) void k_embed(
    const int* __restrict__ nf, const float* __restrict__ semb,
    const float* __restrict__ cemb, const float* __restrict__ pw,
    const float* __restrict__ pb, float* __restrict__ x1)
{
  int gid = blockIdx.x * 256 + threadIdx.x;
  bool valid = gid < NN;
  int i = valid ? gid : NN - 1;
  int sf = nf[2 * i], cf = nf[2 * i + 1];
  float x0[16];
#pragma unroll
  for (int k = 0; k < 8; ++k) x0[k] = semb[sf * 8 + k];
#pragma unroll
  for (int k = 0; k < 8; ++k) x0[8 + k] = cemb[cf * 8 + k];
  float acc[32];
#pragma unroll
  for (int j = 0; j < 32; ++j) acc[j] = pb[j];
#pragma unroll
  for (int k = 0; k < 16; ++k) {
    float xv = x0[k];
#pragma unroll
    for (int j = 0; j < 32; ++j) acc[j] += xv * pw[k * 32 + j];
  }
  if (valid) {
    float4* o = (float4*)(x1 + (size_t)i * 32);
#pragma unroll
    for (int j4 = 0; j4 < 8; ++j4) {
      float4 v;
      v.x = fmaxf(acc[4 * j4 + 0], 0.f);
      v.y = fmaxf(acc[4 * j4 + 1], 0.f);
      v.z = fmaxf(acc[4 * j4 + 2], 0.f);
      v.w = fmaxf(acc[4 * j4 + 3], 0.f);
      o[j4] = v;
    }
  }
}

// ---------- CSR build via bucketed counting sort ----------

// Phase A1: per-bucket edge counts (LDS histogram, 1 global atomic/bucket/block)
__global__ __launch_bounds__(256) void kA_count(
    const int* __restrict__ ei, int* __restrict__ bkt_cnt)
{
  __shared__ int lh[NB];
  for (int b = threadIdx.x; b < NB; b += 256) lh[b] = 0;
  __syncthreads();
  int base = blockIdx.x * EPB;
#pragma unroll
  for (int i = 0; i < EPB / 256; ++i) {
    int e = base + i * 256 + threadIdx.x;
    if (e < NE) atomicAdd(&lh[ei[NE + e] >> BSH], 1);
  }
  __syncthreads();
  for (int b = threadIdx.x; b < NB; b += 256)
    if (lh[b]) atomicAdd(&bkt_cnt[b], lh[b]);
}

// Phase A2: exclusive scan over the 196 bucket counts -> base + cursor
__global__ __launch_bounds__(256) void kA_scan(
    const int* __restrict__ bkt_cnt, int* __restrict__ bkt_base,
    int* __restrict__ bkt_cur)
{
  __shared__ int sm[2][256];
  int t = threadIdx.x;
  int v = (t < NB) ? bkt_cnt[t] : 0;
  sm[0][t] = v;
  __syncthreads();
  int cur = 0;
#pragma unroll
  for (int off = 1; off < 256; off <<= 1) {
    int add = (t >= off) ? sm[cur][t - off] : 0;
    sm[cur ^ 1][t] = sm[cur][t] + add;
    __syncthreads();
    cur ^= 1;
  }
  if (t < NB) {
    int ex = sm[cur][t] - v;
    bkt_base[t] = ex;
    bkt_cur[t] = ex;
  }
  if (t == 0) bkt_base[NB] = NE;
}

// Phase A3: bin edges by bucket; one contiguous run reservation per bucket per
// block -> dense burst writes from one CU.
// pack: src(0-16) | type(17-18) | dst&511 (19-27)
__global__ __launch_bounds__(256) void kA_scatter(
    const int* __restrict__ ei, const int* __restrict__ et,
    int* __restrict__ bkt_cur, int* __restrict__ binned)
{
  __shared__ int packA[EPB];
  __shared__ unsigned char bktA[EPB];
  __shared__ int lh[NB], grun[NB], lcur[NB];
  for (int b = threadIdx.x; b < NB; b += 256) { lh[b] = 0; lcur[b] = 0; }
  __syncthreads();
  int base = blockIdx.x * EPB;
#pragma unroll
  for (int i = 0; i < EPB / 256; ++i) {
    int p = i * 256 + threadIdx.x;
    int e = base + p;
    if (e < NE) {
      int src = ei[e], dst = ei[NE + e], ty = et[e];
      int b = dst >> BSH;
      packA[p] = src | (ty << 17) | ((dst & 511) << 19);
      bktA[p] = (unsigned char)b;
      atomicAdd(&lh[b], 1);
    } else {
      bktA[p] = 255;
    }
  }
  __syncthreads();
  for (int b = threadIdx.x; b < NB; b += 256)
    grun[b] = lh[b] ? atomicAdd(&bkt_cur[b], lh[b]) : 0;
  __syncthreads();
#pragma unroll
  for (int i = 0; i < EPB / 256; ++i) {
    int p = i * 256 + threadIdx.x;
    int b = bktA[p];
    if (b != 255) {
      int off = atomicAdd(&lcur[b], 1);
      binned[grun[b] + off] = packA[p];
    }
  }
}

// Phase B: one workgroup per bucket; exclusive contiguous slice of ep.
__global__ __launch_bounds__(512) void kB_build(
    const int* __restrict__ bkt_base, const int* __restrict__ binned,
    int* __restrict__ rs, int* __restrict__ ep)
{
  __shared__ int stage[CAP];
  __shared__ int ldeg[512], lrs[512], lcur[512];
  __shared__ int sm[2][512];
  int b = blockIdx.x;
  int t = threadIdx.x;
  int p0 = bkt_base[b], p1 = bkt_base[b + 1];
  int cnt = p1 - p0;
  int nodes0 = b << BSH;
  int nnodes = NN - nodes0 < 512 ? NN - nodes0 : 512;
  ldeg[t] = 0;
  lcur[t] = 0;
  __syncthreads();
  for (int p = t; p < cnt; p += 512) {
    int pk = binned[p0 + p];
    if (p < CAP) stage[p] = pk;
    atomicAdd(&ldeg[(pk >> 19) & 511], 1);
  }
  __syncthreads();
  sm[0][t] = ldeg[t];
  __syncthreads();
  int cur = 0;
#pragma unroll
  for (int off = 1; off < 512; off <<= 1) {
    int add = (t >= off) ? sm[cur][t - off] : 0;
    sm[cur ^ 1][t] = sm[cur][t] + add;
    __syncthreads();
    cur ^= 1;
  }
  lrs[t] = p0 + sm[cur][t] - ldeg[t];
  if (t < nnodes) rs[nodes0 + t] = lrs[t];
  if (b == NB - 1 && t == 0) rs[NN] = NE;
  __syncthreads();
  for (int p = t; p < cnt; p += 512) {
    int pk = (p < CAP) ? stage[p] : binned[p0 + p];
    int dl = (pk >> 19) & 511;
    int off = atomicAdd(&lcur[dl], 1);
    ep[lrs[dl] + off] = pk & 0x7FFFF;  // keep src|type bits only
  }
}

// ---------- per-relation mean aggregation: h[d][r][k] = mean_{(s->d,r)} x[s][k] ----------
template <int IN>
__global__ __launch_bounds__(256) void k_agg(
    const float* __restrict__ x, const int* __restrict__ rs,
    const int* __restrict__ ep, float* __restrict__ h)
{
  constexpr int DPW = 64 / IN;  // dst per wave
  int tid = threadIdx.x;
  int wid = (blockIdx.x * 256 + tid) >> 6;
  int lane = tid & 63;
  int k = lane & (IN - 1);
  int half = lane >> (IN == 64 ? 6 : 5);  // 0, or 0/1 when IN=32
  int d = wid * DPW + half;
  if (d >= NN) return;
  int p0 = rs[d], p1 = rs[d + 1];
  float a0 = 0.f, a1 = 0.f, a2 = 0.f;
  int c0 = 0, c1 = 0, c2 = 0;
  int p = p0;
  for (; p + 4 <= p1; p += 4) {
    int e0 = ep[p + 0];
    int e1 = ep[p + 1];
    int e2 = ep[p + 2];
    int e3 = ep[p + 3];
    float v0 = x[(size_t)(e0 & 0x1FFFF) * IN + k];
    float v1 = x[(size_t)(e1 & 0x1FFFF) * IN + k];
    float v2 = x[(size_t)(e2 & 0x1FFFF) * IN + k];
    float v3 = x[(size_t)(e3 & 0x1FFFF) * IN + k];
    int t0 = e0 >> 17, t1 = e1 >> 17, t2 = e2 >> 17, t3 = e3 >> 17;
    a0 += ((t0 == 0) ? v0 : 0.f) + ((t1 == 0) ? v1 : 0.f) +
          ((t2 == 0) ? v2 : 0.f) + ((t3 == 0) ? v3 : 0.f);
    a1 += ((t0 == 1) ? v0 : 0.f) + ((t1 == 1) ? v1 : 0.f) +
          ((t2 == 1) ? v2 : 0.f) + ((t3 == 1) ? v3 : 0.f);
    a2 += ((t0 == 2) ? v0 : 0.f) + ((t1 == 2) ? v1 : 0.f) +
          ((t2 == 2) ? v2 : 0.f) + ((t3 == 2) ? v3 : 0.f);
    c0 += (t0 == 0) + (t1 == 0) + (t2 == 0) + (t3 == 0);
    c1 += (t0 == 1) + (t1 == 1) + (t2 == 1) + (t3 == 1);
    c2 += (t0 == 2) + (t1 == 2) + (t2 == 2) + (t3 == 2);
  }
  for (; p < p1; ++p) {
    int e = ep[p];
    float v = x[(size_t)(e & 0x1FFFF) * IN + k];
    int t = e >> 17;
    a0 += (t == 0) ? v : 0.f;
    a1 += (t == 1) ? v : 0.f;
    a2 += (t == 2) ? v : 0.f;
    c0 += (t == 0);
    c1 += (t == 1);
    c2 += (t == 2);
  }
  float* hd = h + (size_t)d * 3 * IN;
  hd[0 * IN + k] = a0 / (float)(c0 > 0 ? c0 : 1);
  hd[1 * IN + k] = a1 / (float)(c1 > 0 ? c1 : 1);
  hd[2 * IN + k] = a2 / (float)(c2 > 0 ? c2 : 1);
}

// ---------- dense: y[d] = relu(x[d]@root + bias + sum_r h[d][r]@rel_r) ----------
// LDS-staged, transposed. Block = 256 thr = 4 waves covers 64 nodes.
// lane = node (n), wave = j-chunk (j0 = wave*16, readfirstlane -> weight
// addresses are wave-uniform s_loads through the scalar cache).
// x/h rows are loaded ONCE, coalesced, and stored to LDS transposed
// (smem[feature][node], row pad 65 -> <=2-way bank conflicts, free).
// The k-loop then reads 1 ds_read_b32 + 16 FMA per k: no global latency
// inside the hot loop (this was the 82us kernel's stall: 256B-strided row
// reads missing L1 -> exposed L2 latency, VALUBusy 50%).
// LDS = 3*IN rows (49.9KB for IN=64 -> 3 blocks/CU): stage {x,h0,h1},
// compute m=0..2, barrier, restage h2 over the x rows, compute m=3.
template <int IN>
__global__ __launch_bounds__(256) void k_mat(
    const float* __restrict__ x, const float* __restrict__ h,
    const float* __restrict__ root, const float* __restrict__ rel,
    const float* __restrict__ bias, float* __restrict__ y)
{
  __shared__ float smem[3 * IN][65];
  const int tid = threadIdx.x;
  const int node0 = blockIdx.x * 64;
  const int n = tid & 63;
  const int j0 = __builtin_amdgcn_readfirstlane((tid >> 6) * 16);

  constexpr int F4 = IN / 4;  // float4 per node-row of one stream

  // ---- stage x -> rows [0, IN) ----
  for (int idx = tid; idx < 64 * F4; idx += 256) {
    int nn = idx / F4, c4 = idx % F4;
    int node = node0 + nn;
    float4 v = make_float4(0.f, 0.f, 0.f, 0.f);
    if (node < NN) v = *(const float4*)(x + (size_t)node * IN + c4 * 4);
    smem[c4 * 4 + 0][nn] = v.x;
    smem[c4 * 4 + 1][nn] = v.y;
    smem[c4 * 4 + 2][nn] = v.z;
    smem[c4 * 4 + 3][nn] = v.w;
  }
  // ---- stage h0 -> rows [IN, 2IN), h1 -> rows [2IN, 3IN) ----
#pragma unroll
  for (int r = 0; r < 2; ++r) {
    for (int idx = tid; idx < 64 * F4; idx += 256) {
      int nn = idx / F4, c4 = idx % F4;
      int node = node0 + nn;
      float4 v = make_float4(0.f, 0.f, 0.f, 0.f);
      if (node < NN) v = *(const float4*)(h + ((size_t)node * 3 + r) * IN + c4 * 4);
      smem[(1 + r) * IN + c4 * 4 + 0][nn] = v.x;
      smem[(1 + r) * IN + c4 * 4 + 1][nn] = v.y;
      smem[(1 + r) * IN + c4 * 4 + 2][nn] = v.z;
      smem[(1 + r) * IN + c4 * 4 + 3][nn] = v.w;
    }
  }
  __syncthreads();

  float acc[16];
#pragma unroll
  for (int j = 0; j < 16; ++j) acc[j] = bias[j0 + j];

  auto mm = [&](const float* __restrict__ W, int row0) {
#pragma unroll 4
    for (int k = 0; k < IN; ++k) {
      float sk = smem[row0 + k][n];
      const float* w = W + (size_t)k * 64 + j0;
#pragma unroll
      for (int j = 0; j < 16; ++j) acc[j] = fmaf(sk, w[j], acc[j]);
    }
  };

  mm(root, 0);                       // m=0: x @ root
  mm(rel, IN);                       // m=1: h0 @ rel0
  mm(rel + (size_t)IN * 64, 2 * IN); // m=2: h1 @ rel1
  __syncthreads();

  // ---- restage h2 over rows [0, IN) ----
  for (int idx = tid; idx < 64 * F4; idx += 256) {
    int nn = idx / F4, c4 = idx % F4;
    int node = node0 + nn;
    float4 v = make_float4(0.f, 0.f, 0.f, 0.f);
    if (node < NN) v = *(const float4*)(h + ((size_t)node * 3 + 2) * IN + c4 * 4);
    smem[c4 * 4 + 0][nn] = v.x;
    smem[c4 * 4 + 1][nn] = v.y;
    smem[c4 * 4 + 2][nn] = v.z;
    smem[c4 * 4 + 3][nn] = v.w;
  }
  __syncthreads();
  mm(rel + (size_t)2 * IN * 64, 0);  // m=3: h2 @ rel2

  int node = node0 + n;
  if (node < NN) {
    float4* o = (float4*)(y + (size_t)node * 64 + j0);
#pragma unroll
    for (int j4 = 0; j4 < 4; ++j4) {
      float4 v;
      v.x = fmaxf(acc[4 * j4 + 0], 0.f);
      v.y = fmaxf(acc[4 * j4 + 1], 0.f);
      v.z = fmaxf(acc[4 * j4 + 2], 0.f);
      v.w = fmaxf(acc[4 * j4 + 3], 0.f);
      o[j4] = v;
    }
  }
}

// ---------- mean pool over sorted batch ids (run-length reduce, then atomic) ----------
__global__ __launch_bounds__(256) void k_pool(
    const float* __restrict__ x3, const int* __restrict__ batch,
    float* __restrict__ pooled, float* __restrict__ gcnt)
{
  int gwave = (blockIdx.x * 256 + threadIdx.x) >> 6;
  int lane = threadIdx.x & 63;
  int n0 = gwave * 64;
  if (n0 >= NN) return;
  int n1 = n0 + 64 < NN ? n0 + 64 : NN;
  int gcur = batch[n0];
  float acc = 0.f;
  int run = 0;
  for (int n = n0; n < n1; ++n) {
    int g = batch[n];
    if (g != gcur) {
      atomicAdd(&pooled[gcur * 64 + lane], acc);
      if (lane == 0) atomicAdd(&gcnt[gcur], (float)run);
      acc = 0.f; run = 0; gcur = g;
    }
    acc += x3[(size_t)n * 64 + lane];
    ++run;
  }
  atomicAdd(&pooled[gcur * 64 + lane], acc);
  if (lane == 0) atomicAdd(&gcnt[gcur], (float)run);
}

// ---------- classifier ----------
__global__ __launch_bounds__(256) void k_cls(
    const float* __restrict__ pooled, const float* __restrict__ gcnt,
    const float* __restrict__ cw, const float* __restrict__ cb, float* __restrict__ out)
{
  int t = blockIdx.x * 256 + threadIdx.x;
  if (t >= NG * 10) return;
  int g = t / 10, c = t % 10;
  float cf = fmaxf(gcnt[g], 1.f);
  float acc = cb[c];
#pragma unroll 8
  for (int k = 0; k < 64; ++k)
    acc += (pooled[g * 64 + k] / cf) * cw[k * 10 + c];
  out[t] = acc;
}

extern "C" void kernel_launch(void* const* d_in, const int* in_sizes, int n_in,
                              void* d_out, int out_size, void* d_ws, size_t ws_size,
                              hipStream_t stream)
{
  const int* nf = (const int*)d_in[0];
  const int* ei = (const int*)d_in[1];
  const int* et = (const int*)d_in[2];
  const int* batch = (const int*)d_in[3];
  const float* semb = (const float*)d_in[4];
  const float* cemb = (const float*)d_in[5];
  const float* pw = (const float*)d_in[6];
  const float* pb = (const float*)d_in[7];
  const float* root1 = (const float*)d_in[8];
  const float* rel1 = (const float*)d_in[9];
  const float* bias1 = (const float*)d_in[10];
  const float* root2 = (const float*)d_in[11];
  const float* rel2 = (const float*)d_in[12];
  const float* bias2 = (const float*)d_in[13];
  const float* cw = (const float*)d_in[14];
  const float* cb = (const float*)d_in[15];
  float* out = (float*)d_out;

  char* ws = (char*)d_ws;
  size_t off = 0;
  auto alloc = [&](size_t bytes) {
    char* p = ws + off;
    off += (bytes + 255) & ~(size_t)255;
    return p;
  };
  int* bkt_cnt = (int*)alloc((size_t)NB * 4);
  int* bkt_base = (int*)alloc((size_t)(NB + 1) * 4);
  int* bkt_cur = (int*)alloc((size_t)NB * 4);
  int* rs = (int*)alloc((size_t)(NN + 1) * 4);     // row_start
  int* ep = (int*)alloc((size_t)NE * 4);           // packed (src | type<<17), CSR order
  float* xA = (float*)alloc((size_t)NN * 64 * 4);  // x2
  float* xB = (float*)alloc((size_t)NN * 64 * 4);  // x1 ([N,32]) then x3
  float* h = (float*)alloc((size_t)3 * NN * 64 * 4);  // h[d][r][IN]
  float* pooled = (float*)alloc((size_t)NG * 64 * 4);
  float* gcnt = (float*)alloc((size_t)NG * 4);
  int* binned = (int*)h;  // phase-A output; consumed by kB_build before k_agg writes h
  (void)ws_size; (void)in_sizes; (void)n_in; (void)out_size;

  hipMemsetAsync(bkt_cnt, 0, (size_t)NB * 4, stream);
  k_embed<<<(NN + 255) / 256, 256, 0, stream>>>(nf, semb, cemb, pw, pb, xB);

  // CSR build: bucketed counting sort
  kA_count<<<NAB, 256, 0, stream>>>(ei, bkt_cnt);
  kA_scan<<<1, 256, 0, stream>>>(bkt_cnt, bkt_base, bkt_cur);
  kA_scatter<<<NAB, 256, 0, stream>>>(ei, et, bkt_cur, binned);
  kB_build<<<NB, 512, 0, stream>>>(bkt_base, binned, rs, ep);

  int matgrid = (NN + 63) / 64;  // 1563 blocks, 64 nodes each

  // layer 1: x1[N,32] (xB) -> h -> x2[N,64] (xA)
  k_agg<32><<<(NN / 2 + 3) / 4 + 1, 256, 0, stream>>>(xB, rs, ep, h);
  k_mat<32><<<matgrid, 256, 0, stream>>>(xB, h, root1, rel1, bias1, xA);
  // layer 2: x2 (xA) -> h -> x3 (xB)
  k_agg<64><<<(NN + 3) / 4, 256, 0, stream>>>(xA, rs, ep, h);
  k_mat<64><<<matgrid, 256, 0, stream>>>(xA, h, root2, rel2, bias2, xB);

  hipMemsetAsync(pooled, 0, (size_t)NG * 64 * 4, stream);
  hipMemsetAsync(gcnt, 0, (size_t)NG * 4, stream);
  int nwaves = (NN + 63) / 64;
  k_pool<<<(nwaves + 3) / 4, 256, 0, stream>>>(xB, batch, pooled, gcnt);
  k_cls<<<(NG * 10 + 255) / 256, 256, 0, stream>>>(pooled, gcnt, cw, cb, out);
}

// Round 5
// 325.383 us; speedup vs baseline: 1.4441x; 1.0615x over previous
//
#include <hip/hip_runtime.h>

#define NN 100000
#define NE 1600000
#define NG 512

#define BSH 9                         // bucket = dst >> 9 (512 nodes/bucket)
#define NB 196                        // ceil(NN / 512)
#define EPB 8192                      // edges per block in phase A
#define NAB ((NE + EPB - 1) / EPB)    // 196 phase-A blocks
#define CAP 9216                      // LDS staging capacity in kB_build

// ---------- embedding lookup + pre-linear + relu: x1[N,32] ----------
__global__ __launch_bounds__(256) void k_embed(
    const int* __restrict__ nf, const float* __restrict__ semb,
    const float* __restrict__ cemb, const float* __restrict__ pw,
    const float* __restrict__ pb, float* __restrict__ x1)
{
  int gid = blockIdx.x * 256 + threadIdx.x;
  bool valid = gid < NN;
  int i = valid ? gid : NN - 1;
  int sf = nf[2 * i], cf = nf[2 * i + 1];
  float x0[16];
#pragma unroll
  for (int k = 0; k < 8; ++k) x0[k] = semb[sf * 8 + k];
#pragma unroll
  for (int k = 0; k < 8; ++k) x0[8 + k] = cemb[cf * 8 + k];
  float acc[32];
#pragma unroll
  for (int j = 0; j < 32; ++j) acc[j] = pb[j];
#pragma unroll
  for (int k = 0; k < 16; ++k) {
    float xv = x0[k];
#pragma unroll
    for (int j = 0; j < 32; ++j) acc[j] += xv * pw[k * 32 + j];
  }
  if (valid) {
    float4* o = (float4*)(x1 + (size_t)i * 32);
#pragma unroll
    for (int j4 = 0; j4 < 8; ++j4) {
      float4 v;
      v.x = fmaxf(acc[4 * j4 + 0], 0.f);
      v.y = fmaxf(acc[4 * j4 + 1], 0.f);
      v.z = fmaxf(acc[4 * j4 + 2], 0.f);
      v.w = fmaxf(acc[4 * j4 + 3], 0.f);
      o[j4] = v;
    }
  }
}

// ---------- CSR build via bucketed counting sort ----------

// Phase A1: per-bucket edge counts (LDS histogram, 1 global atomic/bucket/block)
__global__ __launch_bounds__(256) void kA_count(
    const int* __restrict__ ei, int* __restrict__ bkt_cnt)
{
  __shared__ int lh[NB];
  for (int b = threadIdx.x; b < NB; b += 256) lh[b] = 0;
  __syncthreads();
  int base = blockIdx.x * EPB;
#pragma unroll
  for (int i = 0; i < EPB / 256; ++i) {
    int e = base + i * 256 + threadIdx.x;
    if (e < NE) atomicAdd(&lh[ei[NE + e] >> BSH], 1);
  }
  __syncthreads();
  for (int b = threadIdx.x; b < NB; b += 256)
    if (lh[b]) atomicAdd(&bkt_cnt[b], lh[b]);
}

// Phase A2: exclusive scan over the 196 bucket counts -> base + cursor
__global__ __launch_bounds__(256) void kA_scan(
    const int* __restrict__ bkt_cnt, int* __restrict__ bkt_base,
    int* __restrict__ bkt_cur)
{
  __shared__ int sm[2][256];
  int t = threadIdx.x;
  int v = (t < NB) ? bkt_cnt[t] : 0;
  sm[0][t] = v;
  __syncthreads();
  int cur = 0;
#pragma unroll
  for (int off = 1; off < 256; off <<= 1) {
    int add = (t >= off) ? sm[cur][t - off] : 0;
    sm[cur ^ 1][t] = sm[cur][t] + add;
    __syncthreads();
    cur ^= 1;
  }
  if (t < NB) {
    int ex = sm[cur][t] - v;
    bkt_base[t] = ex;
    bkt_cur[t] = ex;
  }
  if (t == 0) bkt_base[NB] = NE;
}

// Phase A3: bin edges by bucket; one contiguous run reservation per bucket per
// block -> dense burst writes from one CU.
// pack: src(0-16) | type(17-18) | dst&511 (19-27)
__global__ __launch_bounds__(256) void kA_scatter(
    const int* __restrict__ ei, const int* __restrict__ et,
    int* __restrict__ bkt_cur, int* __restrict__ binned)
{
  __shared__ int packA[EPB];
  __shared__ unsigned char bktA[EPB];
  __shared__ int lh[NB], grun[NB], lcur[NB];
  for (int b = threadIdx.x; b < NB; b += 256) { lh[b] = 0; lcur[b] = 0; }
  __syncthreads();
  int base = blockIdx.x * EPB;
#pragma unroll
  for (int i = 0; i < EPB / 256; ++i) {
    int p = i * 256 + threadIdx.x;
    int e = base + p;
    if (e < NE) {
      int src = ei[e], dst = ei[NE + e], ty = et[e];
      int b = dst >> BSH;
      packA[p] = src | (ty << 17) | ((dst & 511) << 19);
      bktA[p] = (unsigned char)b;
      atomicAdd(&lh[b], 1);
    } else {
      bktA[p] = 255;
    }
  }
  __syncthreads();
  for (int b = threadIdx.x; b < NB; b += 256)
    grun[b] = lh[b] ? atomicAdd(&bkt_cur[b], lh[b]) : 0;
  __syncthreads();
#pragma unroll
  for (int i = 0; i < EPB / 256; ++i) {
    int p = i * 256 + threadIdx.x;
    int b = bktA[p];
    if (b != 255) {
      int off = atomicAdd(&lcur[b], 1);
      binned[grun[b] + off] = packA[p];
    }
  }
}

// Phase B: one workgroup per bucket; exclusive contiguous slice of ep.
__global__ __launch_bounds__(512) void kB_build(
    const int* __restrict__ bkt_base, const int* __restrict__ binned,
    int* __restrict__ rs, int* __restrict__ ep)
{
  __shared__ int stage[CAP];
  __shared__ int ldeg[512], lrs[512], lcur[512];
  __shared__ int sm[2][512];
  int b = blockIdx.x;
  int t = threadIdx.x;
  int p0 = bkt_base[b], p1 = bkt_base[b + 1];
  int cnt = p1 - p0;
  int nodes0 = b << BSH;
  int nnodes = NN - nodes0 < 512 ? NN - nodes0 : 512;
  ldeg[t] = 0;
  lcur[t] = 0;
  __syncthreads();
  for (int p = t; p < cnt; p += 512) {
    int pk = binned[p0 + p];
    if (p < CAP) stage[p] = pk;
    atomicAdd(&ldeg[(pk >> 19) & 511], 1);
  }
  __syncthreads();
  sm[0][t] = ldeg[t];
  __syncthreads();
  int cur = 0;
#pragma unroll
  for (int off = 1; off < 512; off <<= 1) {
    int add = (t >= off) ? sm[cur][t - off] : 0;
    sm[cur ^ 1][t] = sm[cur][t] + add;
    __syncthreads();
    cur ^= 1;
  }
  lrs[t] = p0 + sm[cur][t] - ldeg[t];
  if (t < nnodes) rs[nodes0 + t] = lrs[t];
  if (b == NB - 1 && t == 0) rs[NN] = NE;
  __syncthreads();
  for (int p = t; p < cnt; p += 512) {
    int pk = (p < CAP) ? stage[p] : binned[p0 + p];
    int dl = (pk >> 19) & 511;
    int off = atomicAdd(&lcur[dl], 1);
    ep[lrs[dl] + off] = pk & 0x7FFFF;  // keep src|type bits only
  }
}

// ---------- per-relation mean aggregation: h[d][r][k] = mean_{(s->d,r)} x[s][k] ----------
template <int IN>
__global__ __launch_bounds__(256) void k_agg(
    const float* __restrict__ x, const int* __restrict__ rs,
    const int* __restrict__ ep, float* __restrict__ h)
{
  constexpr int DPW = 64 / IN;  // dst per wave
  int tid = threadIdx.x;
  int wid = (blockIdx.x * 256 + tid) >> 6;
  int lane = tid & 63;
  int k = lane & (IN - 1);
  int half = lane >> (IN == 64 ? 6 : 5);  // 0, or 0/1 when IN=32
  int d = wid * DPW + half;
  if (d >= NN) return;
  int p0 = rs[d], p1 = rs[d + 1];
  float a0 = 0.f, a1 = 0.f, a2 = 0.f;
  int c0 = 0, c1 = 0, c2 = 0;
  int p = p0;
  for (; p + 4 <= p1; p += 4) {
    int e0 = ep[p + 0];
    int e1 = ep[p + 1];
    int e2 = ep[p + 2];
    int e3 = ep[p + 3];
    float v0 = x[(size_t)(e0 & 0x1FFFF) * IN + k];
    float v1 = x[(size_t)(e1 & 0x1FFFF) * IN + k];
    float v2 = x[(size_t)(e2 & 0x1FFFF) * IN + k];
    float v3 = x[(size_t)(e3 & 0x1FFFF) * IN + k];
    int t0 = e0 >> 17, t1 = e1 >> 17, t2 = e2 >> 17, t3 = e3 >> 17;
    a0 += ((t0 == 0) ? v0 : 0.f) + ((t1 == 0) ? v1 : 0.f) +
          ((t2 == 0) ? v2 : 0.f) + ((t3 == 0) ? v3 : 0.f);
    a1 += ((t0 == 1) ? v0 : 0.f) + ((t1 == 1) ? v1 : 0.f) +
          ((t2 == 1) ? v2 : 0.f) + ((t3 == 1) ? v3 : 0.f);
    a2 += ((t0 == 2) ? v0 : 0.f) + ((t1 == 2) ? v1 : 0.f) +
          ((t2 == 2) ? v2 : 0.f) + ((t3 == 2) ? v3 : 0.f);
    c0 += (t0 == 0) + (t1 == 0) + (t2 == 0) + (t3 == 0);
    c1 += (t0 == 1) + (t1 == 1) + (t2 == 1) + (t3 == 1);
    c2 += (t0 == 2) + (t1 == 2) + (t2 == 2) + (t3 == 2);
  }
  for (; p < p1; ++p) {
    int e = ep[p];
    float v = x[(size_t)(e & 0x1FFFF) * IN + k];
    int t = e >> 17;
    a0 += (t == 0) ? v : 0.f;
    a1 += (t == 1) ? v : 0.f;
    a2 += (t == 2) ? v : 0.f;
    c0 += (t == 0);
    c1 += (t == 1);
    c2 += (t == 2);
  }
  float* hd = h + (size_t)d * 3 * IN;
  hd[0 * IN + k] = a0 / (float)(c0 > 0 ? c0 : 1);
  hd[1 * IN + k] = a1 / (float)(c1 > 0 ? c1 : 1);
  hd[2 * IN + k] = a2 / (float)(c2 > 0 ? c2 : 1);
}

// ---------- dense: y[d] = relu(x[d]@root + bias + sum_r h[d][r]@rel_r) ----------
// LDS-staged, transposed, 512 threads = 8 waves per 64 nodes.
// lane = node (n), wave = j-chunk (j0 = wave*8, readfirstlane -> weight
// addresses wave-uniform s_loads through the scalar cache), acc[8].
// R4's version ran 256 thr (4 waves) -> 12 waves/CU, stage latency exposed
// (occupancy 24%, VALUBusy 25%). 8 waves x 3 blocks/CU = 24 waves/CU, and
// h2 is prefetched into REGISTERS during the m=0..2 compute so the restage
// point has no exposed global latency.
// LDS = 3*IN rows x 65 pad (49.9KB IN=64 -> 3 blocks/CU; 25KB IN=32 ->
// wave-limited 4 blocks/CU).
template <int IN>
__global__ __launch_bounds__(512) void k_mat(
    const float* __restrict__ x, const float* __restrict__ h,
    const float* __restrict__ root, const float* __restrict__ rel,
    const float* __restrict__ bias, float* __restrict__ y)
{
  __shared__ float smem[3 * IN][65];
  const int tid = threadIdx.x;
  const int node0 = blockIdx.x * 64;
  const int n = tid & 63;
  const int j0 = __builtin_amdgcn_readfirstlane((tid >> 6) * 8);

  constexpr int F4 = IN / 4;         // float4 per node-row of one stream
  constexpr int NPF = (64 * F4) / 512;  // h2 prefetch float4s per thread (2 or 1)

  // ---- stage x -> rows [0, IN) ----
  for (int idx = tid; idx < 64 * F4; idx += 512) {
    int nn = idx / F4, c4 = idx % F4;
    int node = node0 + nn;
    float4 v = make_float4(0.f, 0.f, 0.f, 0.f);
    if (node < NN) v = *(const float4*)(x + (size_t)node * IN + c4 * 4);
    smem[c4 * 4 + 0][nn] = v.x;
    smem[c4 * 4 + 1][nn] = v.y;
    smem[c4 * 4 + 2][nn] = v.z;
    smem[c4 * 4 + 3][nn] = v.w;
  }
  // ---- stage h0 -> rows [IN, 2IN), h1 -> rows [2IN, 3IN) ----
#pragma unroll
  for (int r = 0; r < 2; ++r) {
    for (int idx = tid; idx < 64 * F4; idx += 512) {
      int nn = idx / F4, c4 = idx % F4;
      int node = node0 + nn;
      float4 v = make_float4(0.f, 0.f, 0.f, 0.f);
      if (node < NN) v = *(const float4*)(h + ((size_t)node * 3 + r) * IN + c4 * 4);
      smem[(1 + r) * IN + c4 * 4 + 0][nn] = v.x;
      smem[(1 + r) * IN + c4 * 4 + 1][nn] = v.y;
      smem[(1 + r) * IN + c4 * 4 + 2][nn] = v.z;
      smem[(1 + r) * IN + c4 * 4 + 3][nn] = v.w;
    }
  }
  __syncthreads();

  // ---- issue h2 prefetch NOW; latency hides under m=0..2 compute ----
  float4 pf[NPF];
#pragma unroll
  for (int u = 0; u < NPF; ++u) {
    int idx = u * 512 + tid;
    int nn = idx / F4, c4 = idx % F4;
    int node = node0 + nn;
    pf[u] = make_float4(0.f, 0.f, 0.f, 0.f);
    if (node < NN) pf[u] = *(const float4*)(h + ((size_t)node * 3 + 2) * IN + c4 * 4);
  }

  float acc[8];
#pragma unroll
  for (int j = 0; j < 8; ++j) acc[j] = bias[j0 + j];

  auto mm = [&](const float* __restrict__ W, int row0) {
#pragma unroll 4
    for (int k = 0; k < IN; ++k) {
      float sk = smem[row0 + k][n];
      const float* w = W + (size_t)k * 64 + j0;
#pragma unroll
      for (int j = 0; j < 8; ++j) acc[j] = fmaf(sk, w[j], acc[j]);
    }
  };

  mm(root, 0);                       // m=0: x @ root
  mm(rel, IN);                       // m=1: h0 @ rel0
  mm(rel + (size_t)IN * 64, 2 * IN); // m=2: h1 @ rel1
  __syncthreads();

  // ---- restage h2 over rows [0, IN) from registers (no global latency) ----
#pragma unroll
  for (int u = 0; u < NPF; ++u) {
    int idx = u * 512 + tid;
    int nn = idx / F4, c4 = idx % F4;
    smem[c4 * 4 + 0][nn] = pf[u].x;
    smem[c4 * 4 + 1][nn] = pf[u].y;
    smem[c4 * 4 + 2][nn] = pf[u].z;
    smem[c4 * 4 + 3][nn] = pf[u].w;
  }
  __syncthreads();
  mm(rel + (size_t)2 * IN * 64, 0);  // m=3: h2 @ rel2

  int node = node0 + n;
  if (node < NN) {
    float4* o = (float4*)(y + (size_t)node * 64 + j0);
    float4 v;
    v.x = fmaxf(acc[0], 0.f);
    v.y = fmaxf(acc[1], 0.f);
    v.z = fmaxf(acc[2], 0.f);
    v.w = fmaxf(acc[3], 0.f);
    o[0] = v;
    v.x = fmaxf(acc[4], 0.f);
    v.y = fmaxf(acc[5], 0.f);
    v.z = fmaxf(acc[6], 0.f);
    v.w = fmaxf(acc[7], 0.f);
    o[1] = v;
  }
}

// ---------- mean pool over sorted batch ids (run-length reduce, then atomic) ----------
__global__ __launch_bounds__(256) void k_pool(
    const float* __restrict__ x3, const int* __restrict__ batch,
    float* __restrict__ pooled, float* __restrict__ gcnt)
{
  int gwave = (blockIdx.x * 256 + threadIdx.x) >> 6;
  int lane = threadIdx.x & 63;
  int n0 = gwave * 64;
  if (n0 >= NN) return;
  int n1 = n0 + 64 < NN ? n0 + 64 : NN;
  int gcur = batch[n0];
  float acc = 0.f;
  int run = 0;
  for (int n = n0; n < n1; ++n) {
    int g = batch[n];
    if (g != gcur) {
      atomicAdd(&pooled[gcur * 64 + lane], acc);
      if (lane == 0) atomicAdd(&gcnt[gcur], (float)run);
      acc = 0.f; run = 0; gcur = g;
    }
    acc += x3[(size_t)n * 64 + lane];
    ++run;
  }
  atomicAdd(&pooled[gcur * 64 + lane], acc);
  if (lane == 0) atomicAdd(&gcnt[gcur], (float)run);
}

// ---------- classifier ----------
__global__ __launch_bounds__(256) void k_cls(
    const float* __restrict__ pooled, const float* __restrict__ gcnt,
    const float* __restrict__ cw, const float* __restrict__ cb, float* __restrict__ out)
{
  int t = blockIdx.x * 256 + threadIdx.x;
  if (t >= NG * 10) return;
  int g = t / 10, c = t % 10;
  float cf = fmaxf(gcnt[g], 1.f);
  float acc = cb[c];
#pragma unroll 8
  for (int k = 0; k < 64; ++k)
    acc += (pooled[g * 64 + k] / cf) * cw[k * 10 + c];
  out[t] = acc;
}

extern "C" void kernel_launch(void* const* d_in, const int* in_sizes, int n_in,
                              void* d_out, int out_size, void* d_ws, size_t ws_size,
                              hipStream_t stream)
{
  const int* nf = (const int*)d_in[0];
  const int* ei = (const int*)d_in[1];
  const int* et = (const int*)d_in[2];
  const int* batch = (const int*)d_in[3];
  const float* semb = (const float*)d_in[4];
  const float* cemb = (const float*)d_in[5];
  const float* pw = (const float*)d_in[6];
  const float* pb = (const float*)d_in[7];
  const float* root1 = (const float*)d_in[8];
  const float* rel1 = (const float*)d_in[9];
  const float* bias1 = (const float*)d_in[10];
  const float* root2 = (const float*)d_in[11];
  const float* rel2 = (const float*)d_in[12];
  const float* bias2 = (const float*)d_in[13];
  const float* cw = (const float*)d_in[14];
  const float* cb = (const float*)d_in[15];
  float* out = (float*)d_out;

  char* ws = (char*)d_ws;
  size_t off = 0;
  auto alloc = [&](size_t bytes) {
    char* p = ws + off;
    off += (bytes + 255) & ~(size_t)255;
    return p;
  };
  int* bkt_cnt = (int*)alloc((size_t)NB * 4);
  int* bkt_base = (int*)alloc((size_t)(NB + 1) * 4);
  int* bkt_cur = (int*)alloc((size_t)NB * 4);
  int* rs = (int*)alloc((size_t)(NN + 1) * 4);     // row_start
  int* ep = (int*)alloc((size_t)NE * 4);           // packed (src | type<<17), CSR order
  float* xA = (float*)alloc((size_t)NN * 64 * 4);  // x2
  float* xB = (float*)alloc((size_t)NN * 64 * 4);  // x1 ([N,32]) then x3
  float* h = (float*)alloc((size_t)3 * NN * 64 * 4);  // h[d][r][IN]
  float* pooled = (float*)alloc((size_t)NG * 64 * 4);
  float* gcnt = (float*)alloc((size_t)NG * 4);
  int* binned = (int*)h;  // phase-A output; consumed by kB_build before k_agg writes h
  (void)ws_size; (void)in_sizes; (void)n_in; (void)out_size;

  hipMemsetAsync(bkt_cnt, 0, (size_t)NB * 4, stream);
  k_embed<<<(NN + 255) / 256, 256, 0, stream>>>(nf, semb, cemb, pw, pb, xB);

  // CSR build: bucketed counting sort
  kA_count<<<NAB, 256, 0, stream>>>(ei, bkt_cnt);
  kA_scan<<<1, 256, 0, stream>>>(bkt_cnt, bkt_base, bkt_cur);
  kA_scatter<<<NAB, 256, 0, stream>>>(ei, et, bkt_cur, binned);
  kB_build<<<NB, 512, 0, stream>>>(bkt_base, binned, rs, ep);

  int matgrid = (NN + 63) / 64;  // 1563 blocks, 64 nodes each

  // layer 1: x1[N,32] (xB) -> h -> x2[N,64] (xA)
  k_agg<32><<<(NN / 2 + 3) / 4 + 1, 256, 0, stream>>>(xB, rs, ep, h);
  k_mat<32><<<matgrid, 512, 0, stream>>>(xB, h, root1, rel1, bias1, xA);
  // layer 2: x2 (xA) -> h -> x3 (xB)
  k_agg<64><<<(NN + 3) / 4, 256, 0, stream>>>(xA, rs, ep, h);
  k_mat<64><<<matgrid, 512, 0, stream>>>(xA, h, root2, rel2, bias2, xB);

  hipMemsetAsync(pooled, 0, (size_t)NG * 64 * 4, stream);
  hipMemsetAsync(gcnt, 0, (size_t)NG * 4, stream);
  int nwaves = (NN + 63) / 64;
  k_pool<<<(nwaves + 3) / 4, 256, 0, stream>>>(xB, batch, pooled, gcnt);
  k_cls<<<(NG * 10 + 255) / 256, 256, 0, stream>>>(pooled, gcnt, cw, cb, out);
}